// Round 18
// baseline (241.086 us; speedup 1.0000x reference)
//
#include <hip/hip_runtime.h>
#include <hip/hip_fp16.h>
#include <cmath>

#define NN 50000
#define NE 800000
#define PADF 96  // fallback local sort cap; P(Poisson(16) > 96) ~ 1e-40
#define NBIN 391     // coarse bins: dst>>7 (dst<50000 -> bin<391)
#define NBLK 391     // edge chunks of 2048 (391*2048 = 800768 >= NE)
#define FCAP 3072    // fine-bucket LDS cap (mean 2048, sigma~45; 3072 = +22 sigma)
// int32-overflow boundary of the reference's argsort key (jax x64 disabled):
// key = dst*50000+src wraps for dst>42949, or dst==42949 && src>=33648.
// VERIFIED (prev session): jax order = rotate(bucket, s0), norm indexed by UNROTATED j
// (rnrm at sorted position idx pairs with j = idx - s0 mod NE, src = RAW src array).
#define DST_HI 42949
#define SRC_CUT 33648
// R4: device-scope atomics write ~32B HBM sectors. R5: 1-block scan = 124us Amdahl.
// R9/R17: split structure (no-sort k_fine + 12500-block k_sortw) = 233.4/233.5us.
// R10-R13: sort-inside-k_fine = 258-259us (per-wave serial bitonic chain, partition-
// invariant). R17 profile: NO steady kernel >43us; cost is the 9-stage serial chain.
// THIS ROUND: overlap k_aux's off-critical-path work (rptr/dout, WT, Xh) into k_part's
// launch (k_part: 3128 waves on 8192-wave chip, ~62% CUs idle) -> aux serial time hides.

__device__ __forceinline__ unsigned short f2h(float f) {  // RNE fp32 -> fp16 (11-bit mantissa)
  __half h = __float2half_rn(f);
  return *reinterpret_cast<unsigned short*>(&h);
}

typedef _Float16 half4 __attribute__((ext_vector_type(4)));
typedef float f32x4 __attribute__((ext_vector_type(4)));

// ---- k_hist: 391 blocks x 512 thr. Coarse hist (dst>>7) per 2048-edge chunk + s0. ----
__global__ __launch_bounds__(512) void k_hist(const int* __restrict__ src, const int* __restrict__ dst,
                                              int* __restrict__ H, int* __restrict__ s0g) {
  __shared__ int hh[NBIN];
  __shared__ int s0l;
  int h = blockIdx.x;
  int t = threadIdx.x;
  if (t < NBIN) hh[t] = 0;
  if (t == 0) s0l = 0;
  __syncthreads();
  int my = 0;
#pragma unroll
  for (int r = 0; r < 4; ++r) {
    int e = h * 2048 + r * 512 + t;
    if (e < NE) {
      int d = dst[e];
      atomicAdd(&hh[d >> 7], 1);             // LDS atomic only
      my += (d < DST_HI) ? 1 : 0;
      my += (d == DST_HI && src[e] < SRC_CUT) ? 1 : 0;
    }
  }
  atomicAdd(&s0l, my);
  __syncthreads();
  if (t < NBIN) H[t * NBLK + h] = hh[t];
  if (t == 0) atomicAdd(s0g, s0l);           // 391 global atomics total: negligible
}

// ---- k_scanrow: parallel row-local scan. 391 blocks; block = one bin's 391-chunk row. ----
__global__ __launch_bounds__(512) void k_scanrow(int* __restrict__ H, int* __restrict__ rowtot) {
  __shared__ int tmp[512];
  int row = blockIdx.x;
  int t = threadIdx.x;
  int v = (t < NBLK) ? H[row * NBLK + t] : 0;
  tmp[t] = v;
  __syncthreads();
  for (int off = 1; off < 512; off <<= 1) {
    int u = (t >= (unsigned)off) ? tmp[t - off] : 0;
    __syncthreads();
    tmp[t] += u;
    __syncthreads();
  }
  if (t < NBLK) H[row * NBLK + t] = tmp[t] - v;   // exclusive within row
  if (t == 511) rowtot[row] = tmp[511];
}

// ---- k_partaux: 725 blocks x 512 thr.
// [0,391): coarse partition by dst>>7 (pos = rbase[bin] + Hrow[bin][chunk] + LDS rank).
// [391,489): rptr + dout (binary search, src sorted). [489,529): WT fp16 transposed.
// [529,725): X -> fp16. Aux blocks fill the ~62% of CUs k_part leaves idle (3128 waves),
// removing k_aux's tail from the serial chain. Outputs needed >=2 stages later. ----
__global__ __launch_bounds__(512) void k_partaux(const float* __restrict__ X, const int* __restrict__ src,
                                                 const int* __restrict__ dst, const float* __restrict__ ew,
                                                 const int* __restrict__ P, const int* __restrict__ rowtot,
                                                 unsigned long long* __restrict__ cmp64,
                                                 int* __restrict__ rptr, float* __restrict__ dout,
                                                 const float* __restrict__ Wz, const float* __restrict__ Wh,
                                                 unsigned short* __restrict__ WT, unsigned short* __restrict__ Xh) {
  __shared__ int loc[NBIN];
  __shared__ int rs[512];
  __shared__ int rbase[NBIN];
  int bid = blockIdx.x;
  int t = threadIdx.x;
  if (bid < 391) {
    int h = bid;
    int v = (t < NBIN) ? rowtot[t] : 0;
    rs[t] = v;
    if (t < NBIN) loc[t] = 0;
    __syncthreads();
    for (int off = 1; off < 512; off <<= 1) {
      int u = (t >= (unsigned)off) ? rs[t - off] : 0;
      __syncthreads();
      rs[t] += u;
      __syncthreads();
    }
    if (t < NBIN) rbase[t] = rs[t] - v;   // exclusive scan of rowtot
    __syncthreads();
#pragma unroll
    for (int r = 0; r < 4; ++r) {
      int e = h * 2048 + r * 512 + t;
      if (e < NE) {
        int d = dst[e];
        int bin = d >> 7;
        int rk = atomicAdd(&loc[bin], 1);               // LDS atomic (unstable rank is fine)
        int pos = rbase[bin] + P[bin * NBLK + h] + rk;
        cmp64[pos] = ((unsigned long long)(d & 127) << 48) |
                     ((unsigned long long)src[e] << 24) | (unsigned long long)e;
      }
    }
  } else if (bid < 489) {
    int i = (bid - 391) * 512 + t;
    if (i >= NN) return;
    int lo = 0, hi = NE;
    while (lo < hi) { int m = (lo + hi) >> 1; if (src[m] < i) lo = m + 1; else hi = m; }
    int lo2 = lo, hi2 = NE;
    while (lo2 < hi2) { int m = (lo2 + hi2) >> 1; if (src[m] < i + 1) lo2 = m + 1; else hi2 = m; }
    rptr[i] = lo;
    if (i == NN - 1) rptr[NN] = lo2;
    float a = 0.f;
    for (int p = lo; p < lo2; ++p) a += ew[p];
    dout[i] = a;
  } else if (bid < 529) {
    int idx = (bid - 489) * 512 + t;  // 40*512 == 160*128 exactly
    int kk = idx >> 7, f = idx & 127;
    int blk = kk >> 5, c = kk & 31;
    const float* W = (f < 64) ? Wz : Wh;
    int fl = f & 63;
    float v;
    if (blk == 0)      v = W[c * 64 + fl] + W[18432 + c * 64 + fl];
    else if (blk == 1) v = W[6144 + c * 64 + fl];
    else if (blk == 2) v = W[18432 + 6144 + c * 64 + fl];
    else if (blk == 3) v = W[2 * 6144 + c * 64 + fl];
    else               v = W[18432 + 2 * 6144 + c * 64 + fl];
    WT[f * 160 + kk] = f2h(v);     // transposed fp16: [n=128][k=160], MFMA B-frag k-contig
  } else {
    // X -> fp16 copy: 1.6M elems, 16/thread
    int tt = (bid - 529) * 512 + t;
    int base = tt * 16;
    if (base >= NN * 32) return;
#pragma unroll
    for (int q = 0; q < 2; ++q) {
      const float4 a = *(const float4*)&X[base + q * 8];
      const float4 b = *(const float4*)&X[base + q * 8 + 4];
      ushort4 o1 = make_ushort4(f2h(a.x), f2h(a.y), f2h(a.z), f2h(a.w));
      ushort4 o2 = make_ushort4(f2h(b.x), f2h(b.y), f2h(b.z), f2h(b.w));
      *(ushort4*)&Xh[base + q * 8] = o1;
      *(ushort4*)&Xh[base + q * 8 + 4] = o2;
    }
  }
}

// ---- k_fine: one block per coarse bucket (128 dst, ~2048 edges), 512 thr, ~51KB LDS.
// Counting sort by dstLow only — NO intra-segment sort (R10-R13 lesson: the bitonic
// belongs in the 12500-block kernel). Emits UNSORTED packed cmp {e, d<<16|src}, sp, din. ----
__global__ __launch_bounds__(512) void k_fine(const int* __restrict__ rowtot, const float* __restrict__ ew,
                                              const unsigned long long* __restrict__ cmp64,
                                              int2* __restrict__ cmp, int* __restrict__ sp,
                                              float* __restrict__ din) {
  __shared__ unsigned long long a1[FCAP], a2[FCAP];   // 48 KB
  __shared__ int fh[128], fcnt[128], fo[129];
  __shared__ int bs[2];
  int cb = blockIdx.x;
  int t = threadIdx.x;
  if (t < 64) {
    int s = 0;
    for (int i = t; i < cb; i += 64) s += rowtot[i];
    s += __shfl_xor(s, 32, 64); s += __shfl_xor(s, 16, 64); s += __shfl_xor(s, 8, 64);
    s += __shfl_xor(s, 4, 64);  s += __shfl_xor(s, 2, 64);  s += __shfl_xor(s, 1, 64);
    if (t == 0) { bs[0] = s; bs[1] = s + rowtot[cb]; }
  }
  if (t < 128) { fh[t] = 0; fcnt[t] = 0; }
  __syncthreads();
  int base = bs[0];
  int m = bs[1] - base;
  if (m > FCAP) m = FCAP;                 // paranoia guard
  for (int i = t; i < m; i += 512) {
    unsigned long long it = cmp64[base + i];
    a1[i] = it;
    atomicAdd(&fh[(int)(it >> 48)], 1);
  }
  __syncthreads();
  // exclusive scan of fh[128] by wave 0 (2 bins/lane)
  if (t < 64) {
    int v0 = fh[t * 2], v1 = fh[t * 2 + 1];
    int pair = v0 + v1;
    int run = pair;
    for (int off = 1; off < 64; off <<= 1) {
      int v = __shfl_up(run, off, 64);
      if (t >= off) run += v;
    }
    int excl = run - pair;
    fo[t * 2] = excl; fo[t * 2 + 1] = excl + v0;
    if (t == 63) fo[128] = excl + pair;   // == m
  }
  __syncthreads();
  for (int i = t; i < m; i += 512) {      // unordered scatter into dst-segments
    unsigned long long it = a1[i];
    int b = (int)(it >> 48);
    int p2 = fo[b] + atomicAdd(&fcnt[b], 1);
    a2[p2] = it;
  }
  // sp emit; bins past NN are empty so fo is flat there (cb=390,t=80 -> sp[NN]=NE).
  if (t < 128) {
    int d = cb * 128 + t;
    if (d <= NN) sp[d] = base + fo[t];
  }
  __syncthreads();
  // emit unsorted packed cmp from a2 (coalesced)
  for (int i = t; i < m; i += 512) {
    unsigned long long it = a2[i];
    int e = (int)(it & 0xFFFFFF);
    int sc = (int)((it >> 24) & 0xFFFF);
    int d = cb * 128 + (int)(it >> 48);
    cmp[base + i] = make_int2(e, (int)(((unsigned)d << 16) | (unsigned)sc));
  }
  // din: 4 lanes per dst (512 thr -> 128 dst), segmented ew sum over [fo[nd], fo[nd+1))
  int nd = t >> 2, ln = t & 3;
  int d = cb * 128 + nd;
  if (d < NN) {
    float s = 0.f;
    int e0 = fo[nd], e1 = fo[nd + 1];
    for (int i = e0 + ln; i < e1; i += 4) s += ew[(int)(a2[i] & 0xFFFFFF)];
    s += __shfl_down(s, 2, 4);
    s += __shfl_down(s, 1, 4);
    if (ln == 0) din[d] = s;
  }
}

// ---- k_sortw: wave-per-dst (12500 blocks x 4 waves — the parallelism the sort needs,
// R9/R17-measured). Coalesced bucket read -> 64-lane bitonic (key = packed (d,src) word,
// which within a bucket orders by src == e-order) -> cnf (coalesced) + cnr (the one
// scatter), weights inline. s0 precomputed in k_hist. ----
__global__ __launch_bounds__(256) void k_sortw(const int* __restrict__ sp, const int2* __restrict__ cmp,
                                               const int* __restrict__ rawsrc,
                                               const float* __restrict__ dout, const float* __restrict__ din,
                                               const int* __restrict__ s0g,
                                               int2* __restrict__ cnf, int2* __restrict__ cnr) {
  int wv = (blockIdx.x * 256 + threadIdx.x) >> 6;
  int lane = threadIdx.x & 63;
  if (wv >= NN) return;
  int b0 = sp[wv], b1 = sp[wv + 1];
  int n = b1 - b0;
  int s0 = s0g[0];
  if (n > 64) {  // 64<n<=96 safety path (never hit at Poisson(16))
    if (lane == 0) {
      int es[PADF]; unsigned ys[PADF];
      int nn = n > PADF ? PADF : n;
      for (int i = 0; i < nn; ++i) { int2 pe = cmp[b0 + i]; es[i] = pe.x; ys[i] = (unsigned)pe.y; }
      for (int i = 1; i < nn; ++i) {
        int ve = es[i]; unsigned vy = ys[i]; int j = i - 1;
        while (j >= 0 && ys[j] > vy) { es[j + 1] = es[j]; ys[j + 1] = ys[j]; --j; }
        es[j + 1] = ve; ys[j + 1] = vy;
      }
      for (int i = 0; i < nn; ++i) {
        int sc = (int)(ys[i] & 0xFFFF);
        cnf[b0 + i] = make_int2(sc, __float_as_int(1.0f / dout[sc]));
        int j = b0 + i - s0; if (j < 0) j += NE;
        cnr[es[i]] = make_int2(wv, __float_as_int(1.0f / din[rawsrc[j]]));
      }
    }
    return;
  }
  unsigned long long k = ~0ULL;
  if (lane < n) {
    int2 pe = cmp[b0 + lane];   // coalesced contiguous read
    k = ((unsigned long long)(unsigned)pe.y << 32) | (unsigned)pe.x;  // key=(d,src), payload=e
  }
  if (n > 1) {
#pragma unroll
    for (int kk = 2; kk <= 64; kk <<= 1) {
#pragma unroll
      for (int j = kk >> 1; j > 0; j >>= 1) {
        unsigned long long o = __shfl_xor(k, j, 64);
        bool lower = (lane & j) == 0;
        bool asc = (lane & kk) == 0;
        bool keepmin = (lower == asc);
        if (keepmin ? (o < k) : (o > k)) k = o;
      }
    }
  }
  if (lane < n) {
    int e = (int)(k & 0xffffffffu);
    int sc = (int)((k >> 32) & 0xFFFF);
    cnf[b0 + lane] = make_int2(sc, __float_as_int(1.0f / dout[sc]));   // coalesced
    int j = b0 + lane - s0; if (j < 0) j += NE;
    cnr[e] = make_int2(wv, __float_as_int(1.0f / din[rawsrc[j]]));     // the one scatter
  }
}

// ---- fused pair of gather props (weight bits in cn.y), fp16-only outputs. ----
__global__ __launch_bounds__(256) void k_prop2(const unsigned short* __restrict__ inA, const int* __restrict__ rpA,
                                               const int2* __restrict__ cnA, unsigned short* __restrict__ outAh,
                                               const unsigned short* __restrict__ inB, const int* __restrict__ rpB,
                                               const int2* __restrict__ cnB, unsigned short* __restrict__ outBh,
                                               const float* __restrict__ sub, float mul) {
  int t = blockIdx.x * 256 + threadIdx.x;
  const int half = NN * 8;
  const unsigned short* in; const int* rp; const int2* cn; unsigned short* outh;
  if (t < half) { in = inA; rp = rpA; cn = cnA; outh = outAh; }
  else          { in = inB; rp = rpB; cn = cnB; outh = outBh; t -= half; }
  int r = t >> 3;
  if (r >= NN) return;
  int lane8 = t & 7;
  int c4 = lane8 * 4;
  int b = rp[r], e2 = rp[r + 1];
  float a0[4] = {0.f, 0.f, 0.f, 0.f}, a1[4] = {0.f, 0.f, 0.f, 0.f};
  int p = b;
#define GATH(cc, ww) { \
    uint2 bv = *(const uint2*)&in[(cc) * 32 + c4]; \
    float2 f01 = __half22float2(*(const __half2*)&bv.x); \
    float2 f23 = __half22float2(*(const __half2*)&bv.y); \
    float* a = (jj & 1) ? a1 : a0; \
    a[0] += (ww) * f01.x; a[1] += (ww) * f01.y; \
    a[2] += (ww) * f23.x; a[3] += (ww) * f23.y; }
  for (; p + 16 <= e2; p += 16) {
    int2 u = cn[p + lane8];              // both chunk-loads in flight before any gather
    int2 v = cn[p + 8 + lane8];
#pragma unroll
    for (int jj = 0; jj < 8; ++jj) {
      int col = __shfl(u.x, jj, 8);
      float w = __int_as_float(__shfl(u.y, jj, 8));
      GATH(col, w)
    }
#pragma unroll
    for (int jj = 0; jj < 8; ++jj) {
      int col = __shfl(v.x, jj, 8);
      float w = __int_as_float(__shfl(v.y, jj, 8));
      GATH(col, w)
    }
  }
  for (; p + 8 <= e2; p += 8) {
    int2 u = cn[p + lane8];
#pragma unroll
    for (int jj = 0; jj < 8; ++jj) {
      int col = __shfl(u.x, jj, 8);
      float w = __int_as_float(__shfl(u.y, jj, 8));
      GATH(col, w)
    }
  }
  for (int jj = 0; p < e2; ++p) {
    int2 c1 = cn[p];
    float w = __int_as_float(c1.y);
    GATH(c1.x, w)
  }
#undef GATH
  float ax = a0[0] + a1[0], ay = a0[1] + a1[1], az = a0[2] + a1[2], aw = a0[3] + a1[3];
  float4 o;
  if (sub) {
    const float4 s = *(const float4*)&sub[r * 32 + c4];
    o.x = mul * ax - s.x; o.y = mul * ay - s.y; o.z = mul * az - s.z; o.w = mul * aw - s.w;
  } else {
    o.x = ax; o.y = ay; o.z = az; o.w = aw;
  }
  ushort4 oh = make_ushort4(f2h(o.x), f2h(o.y), f2h(o.z), f2h(o.w));
  *(ushort4*)&outh[r * 32 + c4] = oh;
}

// ---- MFMA fp16 GEMM + GRU epilogue (unchanged from R9; verified). ----
__global__ __launch_bounds__(256) void k_gemm(const unsigned short* __restrict__ Xh,
                                              const unsigned short* __restrict__ T1oh,
                                              const unsigned short* __restrict__ T1ih,
                                              const unsigned short* __restrict__ T2oh,
                                              const unsigned short* __restrict__ T2ih,
                                              const unsigned short* __restrict__ WT,
                                              const float* __restrict__ bz, const float* __restrict__ bh,
                                              float* __restrict__ out) {
  __shared__ unsigned short wlds[128 * 168];
  const int tid = threadIdx.x;
  for (int i = tid; i < 128 * 20; i += 256) {     // 160 halves = 20 x uint4 per row
    int n = i / 20, o = i % 20;
    *(uint4*)&wlds[n * 168 + o * 8] = *(const uint4*)&WT[n * 160 + o * 8];
  }
  __syncthreads();
  const int l = tid & 63, wid = tid >> 6;
  const int m0 = wid * 16;
  const int rb = blockIdx.x * 64;
  int grow = rb + m0 + (l & 15); if (grow >= NN) grow = NN - 1;   // clamp loads; stores guarded
  const int kg = (l >> 4) * 4;
  f32x4 acc[8];
#pragma unroll
  for (int t = 0; t < 8; ++t) acc[t] = (f32x4){0.f, 0.f, 0.f, 0.f};
  const unsigned short* srcs[5] = {Xh, T1oh, T1ih, T2oh, T2ih};
#pragma unroll
  for (int s = 0; s < 5; ++s) {
    const unsigned short* A = srcs[s];
#pragma unroll
    for (int h2 = 0; h2 < 2; ++h2) {
      const int kk = h2 * 16;
      half4 af = *(const half4*)&A[grow * 32 + kk + kg];
      const int kglob = s * 32 + kk + kg;
#pragma unroll
      for (int t = 0; t < 8; ++t) {
        half4 bf = *(const half4*)&wlds[(t * 16 + (l & 15)) * 168 + kglob];
        acc[t] = __builtin_amdgcn_mfma_f32_16x16x16f16(af, bf, acc[t], 0, 0, 0);
      }
    }
  }
  const int c = l & 15;
#pragma unroll
  for (int t = 0; t < 4; ++t) {
    int col = t * 16 + c;
    float bzv = bz[col], bhv = bh[col];
#pragma unroll
    for (int i = 0; i < 4; ++i) {
      int r = rb + m0 + (l >> 4) * 4 + i;
      if (r < NN) {
        float z = 1.f / (1.f + expf(-(acc[t][i] + bzv)));
        float hv = tanhf(acc[t + 4][i] + bhv);
        out[r * 64 + col] = (1.f - z) * hv;
      }
    }
  }
}

// ---------------- launch ----------------
extern "C" void kernel_launch(void* const* d_in, const int* in_sizes, int n_in,
                              void* d_out, int out_size, void* d_ws, size_t ws_size,
                              hipStream_t stream) {
  const float* X  = (const float*)d_in[0];
  const int*   ei = (const int*)d_in[1];
  const float* ew = (const float*)d_in[2];
  const float* Wz = (const float*)d_in[3];
  const float* bz = (const float*)d_in[4];
  const float* Wh = (const float*)d_in[7];
  const float* bh = (const float*)d_in[8];
  float* out = (float*)d_out;
  const int* src = ei;
  const int* dst = ei + NE;

  char* p = (char*)d_ws;
  auto alloc = [&](size_t bytes) -> char* {
    char* r = p;
    p += (bytes + 255) & ~(size_t)255;
    return r;
  };
  unsigned short* Xh   = (unsigned short*)alloc((size_t)NN * 32 * 2);
  unsigned short* T1oh = (unsigned short*)alloc((size_t)NN * 32 * 2);
  unsigned short* T1ih = (unsigned short*)alloc((size_t)NN * 32 * 2);
  unsigned short* T2oh = (unsigned short*)alloc((size_t)NN * 32 * 2);
  unsigned short* T2ih = (unsigned short*)alloc((size_t)NN * 32 * 2);
  unsigned long long* cmp64 = (unsigned long long*)alloc((size_t)NE * 8);  // coarse-partitioned
  int2*  cmp     = (int2*)alloc((size_t)NE * 8);          // unsorted packed {e, d<<16|src}
  int2*  cnf     = (int2*)alloc((size_t)NE * 8);
  int2*  cnr     = (int2*)alloc((size_t)NE * 8);
  int*   H       = (int*)alloc((size_t)NBIN * NBLK * 4);  // hist -> row-exclusive prefixes
  int*   rowtot  = (int*)alloc(NBIN * 4);
  int*   sp      = (int*)alloc((NN + 1) * 4);
  int*   rptr    = (int*)alloc((NN + 1) * 4);
  float* dout    = (float*)alloc(NN * 4);
  float* din     = (float*)alloc(NN * 4);
  unsigned short* WT = (unsigned short*)alloc(128 * 160 * 2);
  int*   s0g     = (int*)alloc(256);

  hipMemsetAsync(s0g, 0, 4, stream);   // one 4-byte clear; everything else memset-free
  k_hist<<<NBLK, 512, 0, stream>>>(src, dst, H, s0g);
  k_scanrow<<<NBIN, 512, 0, stream>>>(H, rowtot);
  k_partaux<<<725, 512, 0, stream>>>(X, src, dst, ew, H, rowtot, cmp64,
                                     rptr, dout, Wz, Wh, WT, Xh);
  k_fine<<<NBIN, 512, 0, stream>>>(rowtot, ew, cmp64, cmp, sp, din);
  k_sortw<<<12500, 256, 0, stream>>>(sp, cmp, src, dout, din, s0g, cnf, cnr);

  // T1 = P(Xh) both directions, fp16 out only
  k_prop2<<<3125, 256, 0, stream>>>(Xh, sp, cnf, T1oh,
                                    Xh, rptr, cnr, T1ih, nullptr, 1.f);
  // T2 = 2*P(T1h) - X (fused Chebyshev), fp16 out only
  k_prop2<<<3125, 256, 0, stream>>>(T1oh, sp, cnf, T2oh,
                                    T1ih, rptr, cnr, T2ih, X, 2.f);

  k_gemm<<<782, 256, 0, stream>>>(Xh, T1oh, T1ih, T2oh, T2ih, WT, bz, bh, out);
}

// Round 20
// 225.420 us; speedup vs baseline: 1.0695x; 1.0695x over previous
//
#include <hip/hip_runtime.h>
#include <hip/hip_fp16.h>
#include <cmath>

#define NN 50000
#define NE 800000
#define NBIN 391     // coarse bins: dst>>7 (dst<50000 -> bin<391)
#define NBLK 391     // edge chunks of 2048 (391*2048 = 800768 >= NE)
#define FCAP 3072    // fine-bucket LDS cap (mean 2048, sigma~45; 3072 = +22 sigma)
// int32-overflow boundary of the reference's argsort key (jax x64 disabled):
// key = dst*50000+src wraps for dst>42949, or dst==42949 && src>=33648.
// VERIFIED (prev session): jax order = rotate(bucket, s0), norm indexed by UNROTATED j
// (rnrm at sorted position idx pairs with j = idx - s0 mod NE, src = RAW src array).
#define DST_HI 42949
#define SRC_CUT 33648
// R4: device-scope atomics write ~32B HBM sectors. R5: 1-block scan = 124us Amdahl.
// R9/R17: split structure = 233.4/233.5us (session best). R10-R13: the per-wave SERIAL
// bitonic is the villain (58-61us, partition-invariant); R11: emission in k_fine is only
// ~2us marginal; R10: cnr stores NODE, prop2-rev resolves 1/din inline (race-free).
// R18: partition+aux fusion REGRESSED (+7.6us, co-residency interference) — reverted.
// THIS ROUND: kill k_sortw. k_fine ranks each item by PARALLEL count-of-smaller-keys
// (~16 LDS reads/item over 512 thr — no serial wave chain) and emits cnf (unordered,
// fwd sum order is free), cnr {d, rawsrc[j]} via rank position, din. cmp deleted.

__device__ __forceinline__ unsigned short f2h(float f) {  // RNE fp32 -> fp16 (11-bit mantissa)
  __half h = __float2half_rn(f);
  return *reinterpret_cast<unsigned short*>(&h);
}

typedef _Float16 half4 __attribute__((ext_vector_type(4)));
typedef float f32x4 __attribute__((ext_vector_type(4)));

// ---- k_aux: [0,196) rptr+dout | [196,276) WT fp16 transposed | [276,667) X->fp16 |
// [667,1058) coarse hist (391 bins) + s0 accumulation. (R17-measured form.)
__global__ __launch_bounds__(256) void k_aux(const float* __restrict__ X, const int* __restrict__ src,
                                             const int* __restrict__ dst, const float* __restrict__ ew,
                                             int* __restrict__ H,
                                             int* __restrict__ rptr, float* __restrict__ dout,
                                             const float* __restrict__ Wz, const float* __restrict__ Wh,
                                             unsigned short* __restrict__ WT, unsigned short* __restrict__ Xh,
                                             int* __restrict__ s0g) {
  __shared__ int hh[NBIN];
  __shared__ int s0l;
  int bid = blockIdx.x;
  int t = threadIdx.x;
  if (bid >= 667) {
    int h = bid - 667;                       // chunk id in [0, NBLK)
    hh[t] = 0;
    if (t + 256 < NBIN) hh[t + 256] = 0;
    if (t == 0) s0l = 0;
    __syncthreads();
    int my = 0;
#pragma unroll
    for (int r = 0; r < 8; ++r) {
      int e = h * 2048 + r * 256 + t;
      if (e < NE) {
        int d = dst[e];
        atomicAdd(&hh[d >> 7], 1);           // LDS atomic only
        my += (d < DST_HI) ? 1 : 0;
        my += (d == DST_HI && src[e] < SRC_CUT) ? 1 : 0;
      }
    }
    atomicAdd(&s0l, my);
    __syncthreads();
    H[t * NBLK + h] = hh[t];
    if (t + 256 < NBIN) H[(t + 256) * NBLK + h] = hh[t + 256];
    if (t == 0) atomicAdd(s0g, s0l);         // 391 global atomics total: negligible
  } else if (bid < 196) {
    int i = bid * 256 + t;
    if (i >= NN) return;
    int lo = 0, hi = NE;
    while (lo < hi) { int m = (lo + hi) >> 1; if (src[m] < i) lo = m + 1; else hi = m; }
    int lo2 = lo, hi2 = NE;
    while (lo2 < hi2) { int m = (lo2 + hi2) >> 1; if (src[m] < i + 1) lo2 = m + 1; else hi2 = m; }
    rptr[i] = lo;
    if (i == NN - 1) rptr[NN] = lo2;
    float a = 0.f;
    for (int p = lo; p < lo2; ++p) a += ew[p];
    dout[i] = a;
  } else if (bid < 276) {
    int idx = (bid - 196) * 256 + t;  // 80*256 == 160*128 exactly
    int kk = idx >> 7, f = idx & 127;
    int blk = kk >> 5, c = kk & 31;
    const float* W = (f < 64) ? Wz : Wh;
    int fl = f & 63;
    float v;
    if (blk == 0)      v = W[c * 64 + fl] + W[18432 + c * 64 + fl];
    else if (blk == 1) v = W[6144 + c * 64 + fl];
    else if (blk == 2) v = W[18432 + 6144 + c * 64 + fl];
    else if (blk == 3) v = W[2 * 6144 + c * 64 + fl];
    else               v = W[18432 + 2 * 6144 + c * 64 + fl];
    WT[f * 160 + kk] = f2h(v);     // transposed fp16: [n=128][k=160], MFMA B-frag k-contig
  } else {
    // X -> fp16 copy: 1.6M elems, 16/thread
    int tt = (bid - 276) * 256 + t;
    int base = tt * 16;
    if (base >= NN * 32) return;
#pragma unroll
    for (int q = 0; q < 2; ++q) {
      const float4 a = *(const float4*)&X[base + q * 8];
      const float4 b = *(const float4*)&X[base + q * 8 + 4];
      ushort4 o1 = make_ushort4(f2h(a.x), f2h(a.y), f2h(a.z), f2h(a.w));
      ushort4 o2 = make_ushort4(f2h(b.x), f2h(b.y), f2h(b.z), f2h(b.w));
      *(ushort4*)&Xh[base + q * 8] = o1;
      *(ushort4*)&Xh[base + q * 8 + 4] = o2;
    }
  }
}

// ---- k_scanrow: parallel row-local scan. 391 blocks; block = one bin's 391-chunk row. ----
__global__ __launch_bounds__(512) void k_scanrow(int* __restrict__ H, int* __restrict__ rowtot) {
  __shared__ int tmp[512];
  int row = blockIdx.x;
  int t = threadIdx.x;
  int v = (t < NBLK) ? H[row * NBLK + t] : 0;
  tmp[t] = v;
  __syncthreads();
  for (int off = 1; off < 512; off <<= 1) {
    int u = (t >= (unsigned)off) ? tmp[t - off] : 0;
    __syncthreads();
    tmp[t] += u;
    __syncthreads();
  }
  if (t < NBLK) H[row * NBLK + t] = tmp[t] - v;   // exclusive within row
  if (t == 511) rowtot[row] = tmp[511];
}

// ---- k_part: coarse partition by dst>>7. pos = rbase[bin] + Hrow[bin][chunk] + LDS rank. ----
__global__ __launch_bounds__(512) void k_part(const int* __restrict__ src, const int* __restrict__ dst,
                                              const int* __restrict__ P, const int* __restrict__ rowtot,
                                              unsigned long long* __restrict__ cmp64) {
  __shared__ int loc[NBIN];
  __shared__ int rs[512];
  __shared__ int rbase[NBIN];
  int h = blockIdx.x;
  int t = threadIdx.x;
  int v = (t < NBIN) ? rowtot[t] : 0;
  rs[t] = v;
  if (t < NBIN) loc[t] = 0;
  __syncthreads();
  for (int off = 1; off < 512; off <<= 1) {
    int u = (t >= (unsigned)off) ? rs[t - off] : 0;
    __syncthreads();
    rs[t] += u;
    __syncthreads();
  }
  if (t < NBIN) rbase[t] = rs[t] - v;   // exclusive scan of rowtot
  __syncthreads();
#pragma unroll
  for (int r = 0; r < 4; ++r) {
    int e = h * 2048 + r * 512 + t;
    if (e < NE) {
      int d = dst[e];
      int bin = d >> 7;
      int rk = atomicAdd(&loc[bin], 1);               // LDS atomic (unstable rank is fine)
      int pos = rbase[bin] + P[bin * NBLK + h] + rk;
      cmp64[pos] = ((unsigned long long)(d & 127) << 48) |
                   ((unsigned long long)src[e] << 24) | (unsigned long long)e;
    }
  }
}

// ---- k_fine: one block per coarse bucket (128 dst, ~2048 edges), 512 thr, ~51KB LDS.
// Counting sort by dstLow -> a2 segments. Then PARALLEL rank-by-count (16 LDS reads/item,
// no serial wave chain — the R10-R13 bitonic trap avoided) and DIRECT emission:
// cnf[base+i] = {src, 1/dout[src]} (unordered: fwd fp32 sum order ~1ulp), cnr[e] =
// {d, rawsrc[j]} with j from sorted position (rank) - s0 (rawsrc reads ~contiguous),
// din = segmented ew sum (consumed inline by prop2-rev, R10-validated). sp emitted. ----
__global__ __launch_bounds__(512) void k_fine(const int* __restrict__ rowtot, const float* __restrict__ ew,
                                              const unsigned long long* __restrict__ cmp64,
                                              const int* __restrict__ rawsrc, const float* __restrict__ dout,
                                              const int* __restrict__ s0g,
                                              int* __restrict__ sp, float* __restrict__ din,
                                              int2* __restrict__ cnf, int2* __restrict__ cnr) {
  __shared__ unsigned long long a1[FCAP], a2[FCAP];   // 48 KB
  __shared__ int fh[128], fcnt[128], fo[129];
  __shared__ int bs[2];
  int cb = blockIdx.x;
  int t = threadIdx.x;
  if (t < 64) {
    int s = 0;
    for (int i = t; i < cb; i += 64) s += rowtot[i];
    s += __shfl_xor(s, 32, 64); s += __shfl_xor(s, 16, 64); s += __shfl_xor(s, 8, 64);
    s += __shfl_xor(s, 4, 64);  s += __shfl_xor(s, 2, 64);  s += __shfl_xor(s, 1, 64);
    if (t == 0) { bs[0] = s; bs[1] = s + rowtot[cb]; }
  }
  if (t < 128) { fh[t] = 0; fcnt[t] = 0; }
  __syncthreads();
  int base = bs[0];
  int m = bs[1] - base;
  if (m > FCAP) m = FCAP;                 // paranoia guard
  for (int i = t; i < m; i += 512) {
    unsigned long long it = cmp64[base + i];
    a1[i] = it;
    atomicAdd(&fh[(int)(it >> 48)], 1);
  }
  __syncthreads();
  // exclusive scan of fh[128] by wave 0 (2 bins/lane)
  if (t < 64) {
    int v0 = fh[t * 2], v1 = fh[t * 2 + 1];
    int pair = v0 + v1;
    int run = pair;
    for (int off = 1; off < 64; off <<= 1) {
      int v = __shfl_up(run, off, 64);
      if (t >= off) run += v;
    }
    int excl = run - pair;
    fo[t * 2] = excl; fo[t * 2 + 1] = excl + v0;
    if (t == 63) fo[128] = excl + pair;   // == m
  }
  __syncthreads();
  for (int i = t; i < m; i += 512) {      // unordered scatter into dst-segments
    unsigned long long it = a1[i];
    int b = (int)(it >> 48);
    int p2 = fo[b] + atomicAdd(&fcnt[b], 1);
    a2[p2] = it;
  }
  // sp emit; bins past NN are empty so fo is flat there (cb=390,t=80 -> sp[NN]=NE).
  if (t < 128) {
    int d = cb * 128 + t;
    if (d <= NN) sp[d] = base + fo[t];
  }
  __syncthreads();
  const int s0 = s0g[0];
  // parallel rank-by-count + emission (R11: emission ~2us marginal in k_fine)
  for (int i = t; i < m; i += 512) {
    unsigned long long it = a2[i];
    int seg = (int)(it >> 48);
    int f0 = fo[seg], f1 = fo[seg + 1];
    int rank = 0;
    for (int q = f0; q < f1; ++q) rank += (a2[q] < it) ? 1 : 0;   // keys unique
    int e = (int)(it & 0xFFFFFF);
    int sc = (int)((it >> 24) & 0xFFFF);
    int d = cb * 128 + seg;
    cnf[base + i] = make_int2(sc, __float_as_int(1.0f / dout[sc]));   // unordered, coalesced
    int j = base + f0 + rank - s0; if (j < 0) j += NE;
    cnr[e] = make_int2(d, rawsrc[j]);                                 // node; w resolved in prop
  }
  // din: 4 lanes per dst (512 thr -> 128 dst), segmented ew sum over [fo[nd], fo[nd+1))
  int nd = t >> 2, ln = t & 3;
  int d = cb * 128 + nd;
  if (d < NN) {
    float s = 0.f;
    int e0 = fo[nd], e1 = fo[nd + 1];
    for (int i = e0 + ln; i < e1; i += 4) s += ew[(int)(a2[i] & 0xFFFFFF)];
    s += __shfl_down(s, 2, 4);
    s += __shfl_down(s, 1, 4);
    if (ln == 0) din[d] = s;
  }
}

// ---- fused pair of gather props, fp16-only outputs. R10-validated dual mode:
// wi==nullptr: cn.y holds weight bits (fwd / cnf). wi!=nullptr: cn.y holds a NODE id;
// weight = 1/wi[node] (rev / cnr, wi=din — safe: din complete before this kernel). ----
__global__ __launch_bounds__(256) void k_prop2(const unsigned short* __restrict__ inA, const int* __restrict__ rpA,
                                               const int2* __restrict__ cnA, const float* __restrict__ wiA,
                                               unsigned short* __restrict__ outAh,
                                               const unsigned short* __restrict__ inB, const int* __restrict__ rpB,
                                               const int2* __restrict__ cnB, const float* __restrict__ wiB,
                                               unsigned short* __restrict__ outBh,
                                               const float* __restrict__ sub, float mul) {
  int t = blockIdx.x * 256 + threadIdx.x;
  const int half = NN * 8;
  const unsigned short* in; const int* rp; const int2* cn; const float* wi; unsigned short* outh;
  if (t < half) { in = inA; rp = rpA; cn = cnA; wi = wiA; outh = outAh; }
  else          { in = inB; rp = rpB; cn = cnB; wi = wiB; outh = outBh; t -= half; }
  int r = t >> 3;
  if (r >= NN) return;
  int lane8 = t & 7;
  int c4 = lane8 * 4;
  int b = rp[r], e2 = rp[r + 1];
  float a0[4] = {0.f, 0.f, 0.f, 0.f}, a1[4] = {0.f, 0.f, 0.f, 0.f};
  int p = b;
#define GATH(cc, ww) { \
    uint2 bv = *(const uint2*)&in[(cc) * 32 + c4]; \
    float2 f01 = __half22float2(*(const __half2*)&bv.x); \
    float2 f23 = __half22float2(*(const __half2*)&bv.y); \
    float* a = (jj & 1) ? a1 : a0; \
    a[0] += (ww) * f01.x; a[1] += (ww) * f01.y; \
    a[2] += (ww) * f23.x; a[3] += (ww) * f23.y; }
  for (; p + 16 <= e2; p += 16) {
    int2 u = cn[p + lane8];              // both chunk-loads in flight before any gather
    int2 v = cn[p + 8 + lane8];
    float uw = wi ? (1.0f / wi[u.y]) : __int_as_float(u.y);
    float vw = wi ? (1.0f / wi[v.y]) : __int_as_float(v.y);
#pragma unroll
    for (int jj = 0; jj < 8; ++jj) {
      int col = __shfl(u.x, jj, 8);
      float w = __shfl(uw, jj, 8);
      GATH(col, w)
    }
#pragma unroll
    for (int jj = 0; jj < 8; ++jj) {
      int col = __shfl(v.x, jj, 8);
      float w = __shfl(vw, jj, 8);
      GATH(col, w)
    }
  }
  for (; p + 8 <= e2; p += 8) {
    int2 u = cn[p + lane8];
    float uw = wi ? (1.0f / wi[u.y]) : __int_as_float(u.y);
#pragma unroll
    for (int jj = 0; jj < 8; ++jj) {
      int col = __shfl(u.x, jj, 8);
      float w = __shfl(uw, jj, 8);
      GATH(col, w)
    }
  }
  for (int jj = 0; p < e2; ++p) {
    int2 c1 = cn[p];
    float w = wi ? (1.0f / wi[c1.y]) : __int_as_float(c1.y);
    GATH(c1.x, w)
  }
#undef GATH
  float ax = a0[0] + a1[0], ay = a0[1] + a1[1], az = a0[2] + a1[2], aw = a0[3] + a1[3];
  float4 o;
  if (sub) {
    const float4 s = *(const float4*)&sub[r * 32 + c4];
    o.x = mul * ax - s.x; o.y = mul * ay - s.y; o.z = mul * az - s.z; o.w = mul * aw - s.w;
  } else {
    o.x = ax; o.y = ay; o.z = az; o.w = aw;
  }
  ushort4 oh = make_ushort4(f2h(o.x), f2h(o.y), f2h(o.z), f2h(o.w));
  *(ushort4*)&outh[r * 32 + c4] = oh;
}

// ---- MFMA fp16 GEMM + GRU epilogue (unchanged from R9; verified). ----
__global__ __launch_bounds__(256) void k_gemm(const unsigned short* __restrict__ Xh,
                                              const unsigned short* __restrict__ T1oh,
                                              const unsigned short* __restrict__ T1ih,
                                              const unsigned short* __restrict__ T2oh,
                                              const unsigned short* __restrict__ T2ih,
                                              const unsigned short* __restrict__ WT,
                                              const float* __restrict__ bz, const float* __restrict__ bh,
                                              float* __restrict__ out) {
  __shared__ unsigned short wlds[128 * 168];
  const int tid = threadIdx.x;
  for (int i = tid; i < 128 * 20; i += 256) {     // 160 halves = 20 x uint4 per row
    int n = i / 20, o = i % 20;
    *(uint4*)&wlds[n * 168 + o * 8] = *(const uint4*)&WT[n * 160 + o * 8];
  }
  __syncthreads();
  const int l = tid & 63, wid = tid >> 6;
  const int m0 = wid * 16;
  const int rb = blockIdx.x * 64;
  int grow = rb + m0 + (l & 15); if (grow >= NN) grow = NN - 1;   // clamp loads; stores guarded
  const int kg = (l >> 4) * 4;
  f32x4 acc[8];
#pragma unroll
  for (int t = 0; t < 8; ++t) acc[t] = (f32x4){0.f, 0.f, 0.f, 0.f};
  const unsigned short* srcs[5] = {Xh, T1oh, T1ih, T2oh, T2ih};
#pragma unroll
  for (int s = 0; s < 5; ++s) {
    const unsigned short* A = srcs[s];
#pragma unroll
    for (int h2 = 0; h2 < 2; ++h2) {
      const int kk = h2 * 16;
      half4 af = *(const half4*)&A[grow * 32 + kk + kg];
      const int kglob = s * 32 + kk + kg;
#pragma unroll
      for (int t = 0; t < 8; ++t) {
        half4 bf = *(const half4*)&wlds[(t * 16 + (l & 15)) * 168 + kglob];
        acc[t] = __builtin_amdgcn_mfma_f32_16x16x16f16(af, bf, acc[t], 0, 0, 0);
      }
    }
  }
  const int c = l & 15;
#pragma unroll
  for (int t = 0; t < 4; ++t) {
    int col = t * 16 + c;
    float bzv = bz[col], bhv = bh[col];
#pragma unroll
    for (int i = 0; i < 4; ++i) {
      int r = rb + m0 + (l >> 4) * 4 + i;
      if (r < NN) {
        float z = 1.f / (1.f + expf(-(acc[t][i] + bzv)));
        float hv = tanhf(acc[t + 4][i] + bhv);
        out[r * 64 + col] = (1.f - z) * hv;
      }
    }
  }
}

// ---------------- launch ----------------
extern "C" void kernel_launch(void* const* d_in, const int* in_sizes, int n_in,
                              void* d_out, int out_size, void* d_ws, size_t ws_size,
                              hipStream_t stream) {
  const float* X  = (const float*)d_in[0];
  const int*   ei = (const int*)d_in[1];
  const float* ew = (const float*)d_in[2];
  const float* Wz = (const float*)d_in[3];
  const float* bz = (const float*)d_in[4];
  const float* Wh = (const float*)d_in[7];
  const float* bh = (const float*)d_in[8];
  float* out = (float*)d_out;
  const int* src = ei;
  const int* dst = ei + NE;

  char* p = (char*)d_ws;
  auto alloc = [&](size_t bytes) -> char* {
    char* r = p;
    p += (bytes + 255) & ~(size_t)255;
    return r;
  };
  unsigned short* Xh   = (unsigned short*)alloc((size_t)NN * 32 * 2);
  unsigned short* T1oh = (unsigned short*)alloc((size_t)NN * 32 * 2);
  unsigned short* T1ih = (unsigned short*)alloc((size_t)NN * 32 * 2);
  unsigned short* T2oh = (unsigned short*)alloc((size_t)NN * 32 * 2);
  unsigned short* T2ih = (unsigned short*)alloc((size_t)NN * 32 * 2);
  unsigned long long* cmp64 = (unsigned long long*)alloc((size_t)NE * 8);  // coarse-partitioned
  int2*  cnf     = (int2*)alloc((size_t)NE * 8);
  int2*  cnr     = (int2*)alloc((size_t)NE * 8);
  int*   H       = (int*)alloc((size_t)NBIN * NBLK * 4);  // hist -> row-exclusive prefixes
  int*   rowtot  = (int*)alloc(NBIN * 4);
  int*   sp      = (int*)alloc((NN + 1) * 4);
  int*   rptr    = (int*)alloc((NN + 1) * 4);
  float* dout    = (float*)alloc(NN * 4);
  float* din     = (float*)alloc(NN * 4);
  unsigned short* WT = (unsigned short*)alloc(128 * 160 * 2);
  int*   s0g     = (int*)alloc(256);

  hipMemsetAsync(s0g, 0, 4, stream);   // one 4-byte clear; everything else memset-free
  k_aux<<<1058, 256, 0, stream>>>(X, src, dst, ew, H, rptr, dout, Wz, Wh, WT, Xh, s0g);
  k_scanrow<<<NBIN, 512, 0, stream>>>(H, rowtot);
  k_part<<<NBLK, 512, 0, stream>>>(src, dst, H, rowtot, cmp64);
  k_fine<<<NBIN, 512, 0, stream>>>(rowtot, ew, cmp64, src, dout, s0g, sp, din, cnf, cnr);

  // T1 = P(Xh) both directions, fp16 out. Reverse weights resolved via din gather (R10 mode).
  k_prop2<<<3125, 256, 0, stream>>>(Xh, sp, cnf, nullptr, T1oh,
                                    Xh, rptr, cnr, din, T1ih, nullptr, 1.f);
  // T2 = 2*P(T1h) - X (fused Chebyshev), fp16 out only
  k_prop2<<<3125, 256, 0, stream>>>(T1oh, sp, cnf, nullptr, T2oh,
                                    T1ih, rptr, cnr, din, T2ih, X, 2.f);

  k_gemm<<<782, 256, 0, stream>>>(Xh, T1oh, T1ih, T2oh, T2ih, WT, bz, bh, out);
}

// Round 22
// 224.486 us; speedup vs baseline: 1.0739x; 1.0042x over previous
//
#include <hip/hip_runtime.h>
#include <hip/hip_fp16.h>
#include <cmath>

#define NN 50000
#define NE 800000
#define NBIN 391     // coarse bins: dst>>7 (dst<50000 -> bin<391)
#define NBLK 391     // edge chunks of 2048 (391*2048 = 800768 >= NE)
#define FCAP 3072    // fixed slot region per bin (mean 2048, sigma~45; +22 sigma)
// int32-overflow boundary of the reference's argsort key (jax x64 disabled):
// key = dst*50000+src wraps for dst>42949, or dst==42949 && src>=33648.
// VERIFIED (prev session): jax order = rotate(bucket, s0), norm indexed by UNROTATED j
// (rnrm at sorted position idx pairs with j = idx - s0 mod NE, src = RAW src array).
#define DST_HI 42949
#define SRC_CUT 33648
// R4: device-scope atomics write ~32B HBM sectors. R5: 1-block scan = 124us Amdahl.
// R10-R13: per-wave SERIAL bitonic = villain. R18: aux+part co-residency fusion regressed.
// R20: rank-by-count k_fine + no k_sortw = 225.4us (best). Top-5 now ALL harness fills —
// no kernel >43us; cost is the 8-dispatch serial chain. THIS ROUND: fixed-slot binning
// (cmp64[bin*FCAP..]) + block-aggregated global-atomic range claims in k_part2 deletes
// the H table AND k_scanrow (order within bin irrelevant: rank-by-count fixes it).
// Chain: 7 kernels -> 6. ~150K aggregated atomics on 391 counters: few us, ~5MB sectors.

__device__ __forceinline__ unsigned short f2h(float f) {  // RNE fp32 -> fp16 (11-bit mantissa)
  __half h = __float2half_rn(f);
  return *reinterpret_cast<unsigned short*>(&h);
}

typedef _Float16 half4 __attribute__((ext_vector_type(4)));
typedef float f32x4 __attribute__((ext_vector_type(4)));

// ---- k_aux: [0,196) rptr+dout | [196,276) WT fp16 transposed | [276,667) X->fp16.
// (hist phase moved to k_part2; 667 blocks now.) ----
__global__ __launch_bounds__(256) void k_aux(const float* __restrict__ X, const int* __restrict__ src,
                                             const float* __restrict__ ew,
                                             int* __restrict__ rptr, float* __restrict__ dout,
                                             const float* __restrict__ Wz, const float* __restrict__ Wh,
                                             unsigned short* __restrict__ WT, unsigned short* __restrict__ Xh) {
  int bid = blockIdx.x;
  int t = threadIdx.x;
  if (bid < 196) {
    int i = bid * 256 + t;
    if (i >= NN) return;
    int lo = 0, hi = NE;
    while (lo < hi) { int m = (lo + hi) >> 1; if (src[m] < i) lo = m + 1; else hi = m; }
    int lo2 = lo, hi2 = NE;
    while (lo2 < hi2) { int m = (lo2 + hi2) >> 1; if (src[m] < i + 1) lo2 = m + 1; else hi2 = m; }
    rptr[i] = lo;
    if (i == NN - 1) rptr[NN] = lo2;
    float a = 0.f;
    for (int p = lo; p < lo2; ++p) a += ew[p];
    dout[i] = a;
  } else if (bid < 276) {
    int idx = (bid - 196) * 256 + t;  // 80*256 == 160*128 exactly
    int kk = idx >> 7, f = idx & 127;
    int blk = kk >> 5, c = kk & 31;
    const float* W = (f < 64) ? Wz : Wh;
    int fl = f & 63;
    float v;
    if (blk == 0)      v = W[c * 64 + fl] + W[18432 + c * 64 + fl];
    else if (blk == 1) v = W[6144 + c * 64 + fl];
    else if (blk == 2) v = W[18432 + 6144 + c * 64 + fl];
    else if (blk == 3) v = W[2 * 6144 + c * 64 + fl];
    else               v = W[18432 + 2 * 6144 + c * 64 + fl];
    WT[f * 160 + kk] = f2h(v);     // transposed fp16: [n=128][k=160], MFMA B-frag k-contig
  } else {
    // X -> fp16 copy: 1.6M elems, 16/thread
    int tt = (bid - 276) * 256 + t;
    int base = tt * 16;
    if (base >= NN * 32) return;
#pragma unroll
    for (int q = 0; q < 2; ++q) {
      const float4 a = *(const float4*)&X[base + q * 8];
      const float4 b = *(const float4*)&X[base + q * 8 + 4];
      ushort4 o1 = make_ushort4(f2h(a.x), f2h(a.y), f2h(a.z), f2h(a.w));
      ushort4 o2 = make_ushort4(f2h(b.x), f2h(b.y), f2h(b.z), f2h(b.w));
      *(ushort4*)&Xh[base + q * 8] = o1;
      *(ushort4*)&Xh[base + q * 8 + 4] = o2;
    }
  }
}

// ---- k_part2: 391 blocks x 512 thr. Pass1: LDS hist of chunk by bin. Claim: one global
// atomicAdd(gbin[bin], cnt) per (block,bin) -> block's base within the bin's FIXED slot
// region [bin*FCAP, bin*FCAP+FCAP). Pass2: place items (LDS rank), compute s0. Order
// within a bin is arbitrary — k_fine's rank-by-count establishes it. H/scanrow deleted. ----
__global__ __launch_bounds__(512) void k_part2(const int* __restrict__ src, const int* __restrict__ dst,
                                               int* __restrict__ gbin, int* __restrict__ s0g,
                                               unsigned long long* __restrict__ cmp64) {
  __shared__ int loc[NBIN];
  __shared__ int gbase[NBIN];
  __shared__ int s0l;
  int h = blockIdx.x;
  int t = threadIdx.x;
  if (t < NBIN) loc[t] = 0;
  if (t == 0) s0l = 0;
  __syncthreads();
  // pass 1: count per bin
#pragma unroll
  for (int r = 0; r < 4; ++r) {
    int e = h * 2048 + r * 512 + t;
    if (e < NE) atomicAdd(&loc[dst[e] >> 7], 1);
  }
  __syncthreads();
  // claim ranges: one global atomic per touched bin; reset loc for pass 2
  if (t < NBIN) {
    int c = loc[t];
    gbase[t] = (c > 0) ? atomicAdd(&gbin[t], c) : 0;
    loc[t] = 0;
  }
  __syncthreads();
  // pass 2: place + s0 contribution (src read here only)
  int my = 0;
#pragma unroll
  for (int r = 0; r < 4; ++r) {
    int e = h * 2048 + r * 512 + t;
    if (e < NE) {
      int d = dst[e];
      int s = src[e];
      int bin = d >> 7;
      int rk = atomicAdd(&loc[bin], 1);               // LDS atomic (unstable rank is fine)
      int pos = bin * FCAP + gbase[bin] + rk;
      cmp64[pos] = ((unsigned long long)(d & 127) << 48) |
                   ((unsigned long long)s << 24) | (unsigned long long)e;
      my += (d < DST_HI) ? 1 : 0;
      my += (d == DST_HI && s < SRC_CUT) ? 1 : 0;
    }
  }
  atomicAdd(&s0l, my);
  __syncthreads();
  if (t == 0) atomicAdd(s0g, s0l);                    // 391 global atomics total
}

// ---- k_fine: one block per coarse bin (128 dst, ~2048 edges), 512 thr, ~51KB LDS.
// Items at cmp64[cb*FCAP .. cb*FCAP+gbin[cb]). Counting sort by dstLow -> a2 segments;
// PARALLEL rank-by-count (no serial wave chain); DIRECT emission: cnf (unordered),
// cnr {d, rawsrc[j]} via rank position, din (segmented ew sum), sp. Global CSR base =
// 64-lane strided sum over gbin[0..cb) (same cost as the old rowtot sum). ----
__global__ __launch_bounds__(512) void k_fine(const int* __restrict__ gbin, const float* __restrict__ ew,
                                              const unsigned long long* __restrict__ cmp64,
                                              const int* __restrict__ rawsrc, const float* __restrict__ dout,
                                              const int* __restrict__ s0g,
                                              int* __restrict__ sp, float* __restrict__ din,
                                              int2* __restrict__ cnf, int2* __restrict__ cnr) {
  __shared__ unsigned long long a1[FCAP], a2[FCAP];   // 48 KB
  __shared__ int fh[128], fcnt[128], fo[129];
  __shared__ int bs[2];
  int cb = blockIdx.x;
  int t = threadIdx.x;
  if (t < 64) {
    int s = 0;
    for (int i = t; i < cb; i += 64) s += gbin[i];
    s += __shfl_xor(s, 32, 64); s += __shfl_xor(s, 16, 64); s += __shfl_xor(s, 8, 64);
    s += __shfl_xor(s, 4, 64);  s += __shfl_xor(s, 2, 64);  s += __shfl_xor(s, 1, 64);
    if (t == 0) { bs[0] = s; bs[1] = gbin[cb]; }
  }
  if (t < 128) { fh[t] = 0; fcnt[t] = 0; }
  __syncthreads();
  int base = bs[0];                       // global CSR base for this bin
  int m = bs[1];
  if (m > FCAP) m = FCAP;                 // paranoia guard
  const size_t slot = (size_t)cb * FCAP;
  for (int i = t; i < m; i += 512) {
    unsigned long long it = cmp64[slot + i];
    a1[i] = it;
    atomicAdd(&fh[(int)(it >> 48)], 1);
  }
  __syncthreads();
  // exclusive scan of fh[128] by wave 0 (2 bins/lane)
  if (t < 64) {
    int v0 = fh[t * 2], v1 = fh[t * 2 + 1];
    int pair = v0 + v1;
    int run = pair;
    for (int off = 1; off < 64; off <<= 1) {
      int v = __shfl_up(run, off, 64);
      if (t >= off) run += v;
    }
    int excl = run - pair;
    fo[t * 2] = excl; fo[t * 2 + 1] = excl + v0;
    if (t == 63) fo[128] = excl + pair;   // == m
  }
  __syncthreads();
  for (int i = t; i < m; i += 512) {      // unordered scatter into dst-segments
    unsigned long long it = a1[i];
    int b = (int)(it >> 48);
    int p2 = fo[b] + atomicAdd(&fcnt[b], 1);
    a2[p2] = it;
  }
  // sp emit; bins past NN are empty so fo is flat there (cb=390,t=80 -> sp[NN]=NE).
  if (t < 128) {
    int d = cb * 128 + t;
    if (d <= NN) sp[d] = base + fo[t];
  }
  __syncthreads();
  const int s0 = s0g[0];
  // parallel rank-by-count + emission (R11: emission ~2us marginal in k_fine)
  for (int i = t; i < m; i += 512) {
    unsigned long long it = a2[i];
    int seg = (int)(it >> 48);
    int f0 = fo[seg], f1 = fo[seg + 1];
    int rank = 0;
    for (int q = f0; q < f1; ++q) rank += (a2[q] < it) ? 1 : 0;   // keys unique
    int e = (int)(it & 0xFFFFFF);
    int sc = (int)((it >> 24) & 0xFFFF);
    int d = cb * 128 + seg;
    cnf[base + i] = make_int2(sc, __float_as_int(1.0f / dout[sc]));   // unordered, coalesced
    int j = base + f0 + rank - s0; if (j < 0) j += NE;
    cnr[e] = make_int2(d, rawsrc[j]);                                 // node; w resolved in prop
  }
  // din: 4 lanes per dst (512 thr -> 128 dst), segmented ew sum over [fo[nd], fo[nd+1))
  int nd = t >> 2, ln = t & 3;
  int d = cb * 128 + nd;
  if (d < NN) {
    float s = 0.f;
    int e0 = fo[nd], e1 = fo[nd + 1];
    for (int i = e0 + ln; i < e1; i += 4) s += ew[(int)(a2[i] & 0xFFFFFF)];
    s += __shfl_down(s, 2, 4);
    s += __shfl_down(s, 1, 4);
    if (ln == 0) din[d] = s;
  }
}

// ---- fused pair of gather props, fp16-only outputs. R10-validated dual mode:
// wi==nullptr: cn.y holds weight bits (fwd / cnf). wi!=nullptr: cn.y holds a NODE id;
// weight = 1/wi[node] (rev / cnr, wi=din — safe: din complete before this kernel). ----
__global__ __launch_bounds__(256) void k_prop2(const unsigned short* __restrict__ inA, const int* __restrict__ rpA,
                                               const int2* __restrict__ cnA, const float* __restrict__ wiA,
                                               unsigned short* __restrict__ outAh,
                                               const unsigned short* __restrict__ inB, const int* __restrict__ rpB,
                                               const int2* __restrict__ cnB, const float* __restrict__ wiB,
                                               unsigned short* __restrict__ outBh,
                                               const float* __restrict__ sub, float mul) {
  int t = blockIdx.x * 256 + threadIdx.x;
  const int half = NN * 8;
  const unsigned short* in; const int* rp; const int2* cn; const float* wi; unsigned short* outh;
  if (t < half) { in = inA; rp = rpA; cn = cnA; wi = wiA; outh = outAh; }
  else          { in = inB; rp = rpB; cn = cnB; wi = wiB; outh = outBh; t -= half; }
  int r = t >> 3;
  if (r >= NN) return;
  int lane8 = t & 7;
  int c4 = lane8 * 4;
  int b = rp[r], e2 = rp[r + 1];
  float a0[4] = {0.f, 0.f, 0.f, 0.f}, a1[4] = {0.f, 0.f, 0.f, 0.f};
  int p = b;
#define GATH(cc, ww) { \
    uint2 bv = *(const uint2*)&in[(cc) * 32 + c4]; \
    float2 f01 = __half22float2(*(const __half2*)&bv.x); \
    float2 f23 = __half22float2(*(const __half2*)&bv.y); \
    float* a = (jj & 1) ? a1 : a0; \
    a[0] += (ww) * f01.x; a[1] += (ww) * f01.y; \
    a[2] += (ww) * f23.x; a[3] += (ww) * f23.y; }
  for (; p + 16 <= e2; p += 16) {
    int2 u = cn[p + lane8];              // both chunk-loads in flight before any gather
    int2 v = cn[p + 8 + lane8];
    float uw = wi ? (1.0f / wi[u.y]) : __int_as_float(u.y);
    float vw = wi ? (1.0f / wi[v.y]) : __int_as_float(v.y);
#pragma unroll
    for (int jj = 0; jj < 8; ++jj) {
      int col = __shfl(u.x, jj, 8);
      float w = __shfl(uw, jj, 8);
      GATH(col, w)
    }
#pragma unroll
    for (int jj = 0; jj < 8; ++jj) {
      int col = __shfl(v.x, jj, 8);
      float w = __shfl(vw, jj, 8);
      GATH(col, w)
    }
  }
  for (; p + 8 <= e2; p += 8) {
    int2 u = cn[p + lane8];
    float uw = wi ? (1.0f / wi[u.y]) : __int_as_float(u.y);
#pragma unroll
    for (int jj = 0; jj < 8; ++jj) {
      int col = __shfl(u.x, jj, 8);
      float w = __shfl(uw, jj, 8);
      GATH(col, w)
    }
  }
  for (int jj = 0; p < e2; ++p) {
    int2 c1 = cn[p];
    float w = wi ? (1.0f / wi[c1.y]) : __int_as_float(c1.y);
    GATH(c1.x, w)
  }
#undef GATH
  float ax = a0[0] + a1[0], ay = a0[1] + a1[1], az = a0[2] + a1[2], aw = a0[3] + a1[3];
  float4 o;
  if (sub) {
    const float4 s = *(const float4*)&sub[r * 32 + c4];
    o.x = mul * ax - s.x; o.y = mul * ay - s.y; o.z = mul * az - s.z; o.w = mul * aw - s.w;
  } else {
    o.x = ax; o.y = ay; o.z = az; o.w = aw;
  }
  ushort4 oh = make_ushort4(f2h(o.x), f2h(o.y), f2h(o.z), f2h(o.w));
  *(ushort4*)&outh[r * 32 + c4] = oh;
}

// ---- MFMA fp16 GEMM + GRU epilogue (unchanged from R9; verified). ----
__global__ __launch_bounds__(256) void k_gemm(const unsigned short* __restrict__ Xh,
                                              const unsigned short* __restrict__ T1oh,
                                              const unsigned short* __restrict__ T1ih,
                                              const unsigned short* __restrict__ T2oh,
                                              const unsigned short* __restrict__ T2ih,
                                              const unsigned short* __restrict__ WT,
                                              const float* __restrict__ bz, const float* __restrict__ bh,
                                              float* __restrict__ out) {
  __shared__ unsigned short wlds[128 * 168];
  const int tid = threadIdx.x;
  for (int i = tid; i < 128 * 20; i += 256) {     // 160 halves = 20 x uint4 per row
    int n = i / 20, o = i % 20;
    *(uint4*)&wlds[n * 168 + o * 8] = *(const uint4*)&WT[n * 160 + o * 8];
  }
  __syncthreads();
  const int l = tid & 63, wid = tid >> 6;
  const int m0 = wid * 16;
  const int rb = blockIdx.x * 64;
  int grow = rb + m0 + (l & 15); if (grow >= NN) grow = NN - 1;   // clamp loads; stores guarded
  const int kg = (l >> 4) * 4;
  f32x4 acc[8];
#pragma unroll
  for (int t = 0; t < 8; ++t) acc[t] = (f32x4){0.f, 0.f, 0.f, 0.f};
  const unsigned short* srcs[5] = {Xh, T1oh, T1ih, T2oh, T2ih};
#pragma unroll
  for (int s = 0; s < 5; ++s) {
    const unsigned short* A = srcs[s];
#pragma unroll
    for (int h2 = 0; h2 < 2; ++h2) {
      const int kk = h2 * 16;
      half4 af = *(const half4*)&A[grow * 32 + kk + kg];
      const int kglob = s * 32 + kk + kg;
#pragma unroll
      for (int t = 0; t < 8; ++t) {
        half4 bf = *(const half4*)&wlds[(t * 16 + (l & 15)) * 168 + kglob];
        acc[t] = __builtin_amdgcn_mfma_f32_16x16x16f16(af, bf, acc[t], 0, 0, 0);
      }
    }
  }
  const int c = l & 15;
#pragma unroll
  for (int t = 0; t < 4; ++t) {
    int col = t * 16 + c;
    float bzv = bz[col], bhv = bh[col];
#pragma unroll
    for (int i = 0; i < 4; ++i) {
      int r = rb + m0 + (l >> 4) * 4 + i;
      if (r < NN) {
        float z = 1.f / (1.f + expf(-(acc[t][i] + bzv)));
        float hv = tanhf(acc[t + 4][i] + bhv);
        out[r * 64 + col] = (1.f - z) * hv;
      }
    }
  }
}

// ---------------- launch ----------------
extern "C" void kernel_launch(void* const* d_in, const int* in_sizes, int n_in,
                              void* d_out, int out_size, void* d_ws, size_t ws_size,
                              hipStream_t stream) {
  const float* X  = (const float*)d_in[0];
  const int*   ei = (const int*)d_in[1];
  const float* ew = (const float*)d_in[2];
  const float* Wz = (const float*)d_in[3];
  const float* bz = (const float*)d_in[4];
  const float* Wh = (const float*)d_in[7];
  const float* bh = (const float*)d_in[8];
  float* out = (float*)d_out;
  const int* src = ei;
  const int* dst = ei + NE;

  char* p = (char*)d_ws;
  auto alloc = [&](size_t bytes) -> char* {
    char* r = p;
    p += (bytes + 255) & ~(size_t)255;
    return r;
  };
  unsigned short* Xh   = (unsigned short*)alloc((size_t)NN * 32 * 2);
  unsigned short* T1oh = (unsigned short*)alloc((size_t)NN * 32 * 2);
  unsigned short* T1ih = (unsigned short*)alloc((size_t)NN * 32 * 2);
  unsigned short* T2oh = (unsigned short*)alloc((size_t)NN * 32 * 2);
  unsigned short* T2ih = (unsigned short*)alloc((size_t)NN * 32 * 2);
  unsigned long long* cmp64 = (unsigned long long*)alloc((size_t)NBIN * FCAP * 8);  // fixed slots
  int2*  cnf     = (int2*)alloc((size_t)NE * 8);
  int2*  cnr     = (int2*)alloc((size_t)NE * 8);
  int*   gbin    = (int*)alloc((NBIN + 1) * 4);           // +1: s0g rides at gbin[NBIN]
  int*   sp      = (int*)alloc((NN + 1) * 4);
  int*   rptr    = (int*)alloc((NN + 1) * 4);
  float* dout    = (float*)alloc(NN * 4);
  float* din     = (float*)alloc(NN * 4);
  unsigned short* WT = (unsigned short*)alloc(128 * 160 * 2);
  int*   s0g     = gbin + NBIN;

  hipMemsetAsync(gbin, 0, (NBIN + 1) * 4, stream);   // one 1.6KB clear (gbin + s0g)
  k_aux<<<667, 256, 0, stream>>>(X, src, ew, rptr, dout, Wz, Wh, WT, Xh);
  k_part2<<<NBLK, 512, 0, stream>>>(src, dst, gbin, s0g, cmp64);
  k_fine<<<NBIN, 512, 0, stream>>>(gbin, ew, cmp64, src, dout, s0g, sp, din, cnf, cnr);

  // T1 = P(Xh) both directions, fp16 out. Reverse weights resolved via din gather (R10 mode).
  k_prop2<<<3125, 256, 0, stream>>>(Xh, sp, cnf, nullptr, T1oh,
                                    Xh, rptr, cnr, din, T1ih, nullptr, 1.f);
  // T2 = 2*P(T1h) - X (fused Chebyshev), fp16 out only
  k_prop2<<<3125, 256, 0, stream>>>(T1oh, sp, cnf, nullptr, T2oh,
                                    T1ih, rptr, cnr, din, T2ih, X, 2.f);

  k_gemm<<<782, 256, 0, stream>>>(Xh, T1oh, T1ih, T2oh, T2ih, WT, bz, bh, out);
}